// Round 1
// baseline (434.417 us; speedup 1.0000x reference)
//
#include <hip/hip_runtime.h>
#include <hip/hip_bf16.h>
#include <math.h>

// Problem constants (from reference): B=32, L=688, M=4, C=32
#define BB 32
#define LL 688
#define MM 4
#define CC 32

struct Accum {
    float cls_sum;          // sum of per-row cls losses (divide by B*L)
    float ptr_sum;          // sum of masked pointer losses
    unsigned int ptr_cnt;   // count of nonzero masked pointer losses
    unsigned int pad;
};

// ---------------- cls loss: log_softmax over C=32 per row ----------------
// 8 rows per 256-thread block; each 32-lane sub-group handles one row.
__global__ __launch_bounds__(256) void cls_kernel(const float* __restrict__ tag_logits,
                                                  const int* __restrict__ tag_targets,
                                                  Accum* __restrict__ acc) {
    __shared__ float red[8];
    const int group = threadIdx.x >> 5;
    const int lane  = threadIdx.x & 31;
    const int row   = blockIdx.x * 8 + group;
    if (row < BB * LL) {
        float x = tag_logits[(size_t)row * CC + lane];
        float m = x;
        #pragma unroll
        for (int off = 16; off >= 1; off >>= 1)
            m = fmaxf(m, __shfl_xor(m, off, 32));
        float s = expf(x - m);
        #pragma unroll
        for (int off = 16; off >= 1; off >>= 1)
            s += __shfl_xor(s, off, 32);
        int tgt = tag_targets[row];
        float xt = __shfl(x, tgt, 32);       // logit at target class
        if (lane == 0)
            red[group] = (m + logf(s)) - xt; // -logp[target]
    }
    __syncthreads();
    if (threadIdx.x == 0) {
        float t = 0.f;
        #pragma unroll
        for (int i = 0; i < 8; ++i) t += red[i];
        atomicAdd(&acc->cls_sum, t);
    }
}

// ---------------- pointer loss: one wave64 per (b,r) row of L=688 --------
// Row = 172 float4; lane l holds vec4 indices {l, l+64, l+128(<172)} in regs.
__global__ __launch_bounds__(256) void ptr_kernel(const float* __restrict__ pl,
                                                  const int* __restrict__ box,
                                                  const int* __restrict__ dtm,
                                                  Accum* __restrict__ acc) {
    const int wave = threadIdx.x >> 6;
    const int lane = threadIdx.x & 63;
    const int row  = blockIdx.x * 4 + wave;
    if (row >= BB * LL) return;
    const int b = row / LL;

    const float4* rowp  = (const float4*)(pl + (size_t)row * LL);
    const int*    mrow  = dtm + b * (2 * LL) + LL;        // seq_mask[b, :]
    const int4*   maskp = (const int4*)mrow;

    const float4 v0 = rowp[lane];
    const float4 v1 = rowp[lane + 64];
    const bool has2 = (lane < 172 - 128);
    const float4 v2 = has2 ? rowp[lane + 128]
                           : make_float4(-INFINITY, -INFINITY, -INFINITY, -INFINITY);

    // unmasked row max
    float mx = fmaxf(fmaxf(fmaxf(v0.x, v0.y), fmaxf(v0.z, v0.w)),
                     fmaxf(fmaxf(v1.x, v1.y), fmaxf(v1.z, v1.w)));
    mx = fmaxf(mx, fmaxf(fmaxf(v2.x, v2.y), fmaxf(v2.z, v2.w)));
    #pragma unroll
    for (int off = 32; off >= 1; off >>= 1)
        mx = fmaxf(mx, __shfl_xor(mx, off));

    // masked exp-sum
    const int4 m0 = maskp[lane];
    const int4 m1 = maskp[lane + 64];
    const int4 m2 = has2 ? maskp[lane + 128] : make_int4(0, 0, 0, 0);
    float s = 0.f;
    if (m0.x) s += expf(v0.x - mx);
    if (m0.y) s += expf(v0.y - mx);
    if (m0.z) s += expf(v0.z - mx);
    if (m0.w) s += expf(v0.w - mx);
    if (m1.x) s += expf(v1.x - mx);
    if (m1.y) s += expf(v1.y - mx);
    if (m1.z) s += expf(v1.z - mx);
    if (m1.w) s += expf(v1.w - mx);
    if (m2.x) s += expf(v2.x - mx);
    if (m2.y) s += expf(v2.y - mx);
    if (m2.z) s += expf(v2.z - mx);
    if (m2.w) s += expf(v2.w - mx);
    #pragma unroll
    for (int off = 32; off >= 1; off >>= 1)
        s += __shfl_xor(s, off);

    if (lane == 0) {
        const float denom = s + 1e-10f;
        const int* bx = box + (size_t)row * MM;
        int t0 = -1, t1 = -1, t2 = -1;   // seen (deduped) target columns
        float lsum = 0.f;
        int lcnt = 0;
        #pragma unroll
        for (int mi = 0; mi < MM; ++mi) {
            int t = bx[mi];
            if (t < 0) continue;                 // invalid
            if (t > LL - 1) t = LL - 1;          // clip (defensive)
            if (t == t0 || t == t1 || t == t2) continue;  // set semantics
            if (t0 < 0) t0 = t; else if (t1 < 0) t1 = t; else t2 = t;
            if (!mrow[t]) continue;              // seq_mask gate
            const float xj = pl[(size_t)row * LL + t];
            const float p = expf(xj - mx) / denom + 1e-10f;
            const float v = -logf(p);
            lsum += v;
            if (v != 0.0f) lcnt++;               // masked != 0 counting
        }
        if (lcnt) {
            atomicAdd(&acc->ptr_sum, lsum);
            atomicAdd(&acc->ptr_cnt, (unsigned)lcnt);
        }
    }
}

// ---------------- empty-pointer BCE + final combine ----------------------
__global__ __launch_bounds__(256) void final_kernel(const float* __restrict__ epl,
                                                    const int* __restrict__ dtm,
                                                    const int* __restrict__ am,
                                                    const Accum* __restrict__ acc,
                                                    float* __restrict__ out) {
    __shared__ float sb[256], sv[256];
    float bsum = 0.f, vsum = 0.f;
    for (int i = threadIdx.x; i < BB * LL; i += 256) {
        const int b = i / LL;
        const int j = i - b * LL;
        const int off = b * (2 * LL) + LL + j;
        const int seq2  = am[off];
        const int data2 = dtm[off];
        const float x = epl[i];
        const float tgt = (seq2 && !data2) ? 1.f : 0.f;
        const float bce = fmaxf(x, 0.f) - x * tgt + log1pf(expf(-fabsf(x)));
        if (seq2) { bsum += bce; vsum += 1.f; }
    }
    sb[threadIdx.x] = bsum;
    sv[threadIdx.x] = vsum;
    __syncthreads();
    for (int stride = 128; stride >= 1; stride >>= 1) {
        if (threadIdx.x < stride) {
            sb[threadIdx.x] += sb[threadIdx.x + stride];
            sv[threadIdx.x] += sv[threadIdx.x + stride];
        }
        __syncthreads();
    }
    if (threadIdx.x == 0) {
        const float cls = acc->cls_sum / (float)(BB * LL);
        const unsigned cnt = acc->ptr_cnt;
        const float ptr = (cnt == 0) ? 0.f : acc->ptr_sum / (float)cnt;
        const float emp = sb[0] / fmaxf(sv[0], 1.f);
        out[0] = cls + ptr + emp;
        out[1] = cls;
        out[2] = ptr;
        out[3] = emp;
    }
}

extern "C" void kernel_launch(void* const* d_in, const int* in_sizes, int n_in,
                              void* d_out, int out_size, void* d_ws, size_t ws_size,
                              hipStream_t stream) {
    const float* tag_logits           = (const float*)d_in[0];
    const float* pointer_logits       = (const float*)d_in[1];
    const float* empty_pointer_logits = (const float*)d_in[2];
    const int*   tag_targets          = (const int*)d_in[3];
    const int*   box_indices          = (const int*)d_in[4];
    const int*   data_tag_mask        = (const int*)d_in[5];
    const int*   attention_mask       = (const int*)d_in[6];
    float* out = (float*)d_out;
    Accum* acc = (Accum*)d_ws;

    hipMemsetAsync(d_ws, 0, sizeof(Accum), stream);

    const int rows = BB * LL;                    // 22016
    cls_kernel<<<rows / 8, 256, 0, stream>>>(tag_logits, tag_targets, acc);
    ptr_kernel<<<rows / 4, 256, 0, stream>>>(pointer_logits, box_indices,
                                             data_tag_mask, acc);
    final_kernel<<<1, 256, 0, stream>>>(empty_pointer_logits, data_tag_mask,
                                        attention_mask, acc, out);
}

// Round 2
// 118.881 us; speedup vs baseline: 3.6542x; 3.6542x over previous
//
#include <hip/hip_runtime.h>
#include <hip/hip_bf16.h>
#include <math.h>

// Problem constants (from reference): B=32, L=688, M=4, C=32
#define BB 32
#define LL 688
#define MM 4
#define CC 32
#define ROWS (BB * LL)       // 22016
#define WPB 4                // waves per block (256 threads)
#define NBLK (ROWS / WPB)    // 5504 blocks

struct Partial { float4 a; float4 b; };  // a={cls,ptr,cnt,bce} b={vm,-,-,-}

// One wave64 per row r in [0, B*L):
//   * pointer loss row: max, masked exp-sum, <=4 gathered targets
//   * cls loss row (tag_logits[r, 0:32])  -- same row index
//   * empty-pointer BCE element r
// Block reduces 4 waves -> one 32B partial. NO global atomics.
__global__ __launch_bounds__(256) void fused_kernel(
    const float* __restrict__ tag_logits,
    const float* __restrict__ pl,
    const float* __restrict__ epl,
    const int* __restrict__ tag_targets,
    const int* __restrict__ box,
    const int* __restrict__ dtm,
    const int* __restrict__ am,
    Partial* __restrict__ partials)
{
    __shared__ float red[WPB][5];
    const int wave = threadIdx.x >> 6;
    const int lane = threadIdx.x & 63;
    const int row  = blockIdx.x * WPB + wave;
    const int b    = row / LL;
    const int j    = row - b * LL;

    // ---------------- pointer loss row ----------------
    const float4* rowp  = (const float4*)(pl + (size_t)row * LL);
    const int*    mrow  = dtm + b * (2 * LL) + LL;     // seq_mask[b,:]
    const int4*   maskp = (const int4*)mrow;

    const float4 v0 = rowp[lane];
    const float4 v1 = rowp[lane + 64];
    const bool has2 = (lane < 172 - 128);
    const float4 v2 = has2 ? rowp[lane + 128]
                           : make_float4(-INFINITY, -INFINITY, -INFINITY, -INFINITY);

    float mx = fmaxf(fmaxf(fmaxf(v0.x, v0.y), fmaxf(v0.z, v0.w)),
                     fmaxf(fmaxf(v1.x, v1.y), fmaxf(v1.z, v1.w)));
    mx = fmaxf(mx, fmaxf(fmaxf(v2.x, v2.y), fmaxf(v2.z, v2.w)));
    #pragma unroll
    for (int off = 32; off >= 1; off >>= 1)
        mx = fmaxf(mx, __shfl_xor(mx, off));

    const int4 m0 = maskp[lane];
    const int4 m1 = maskp[lane + 64];
    const int4 m2 = has2 ? maskp[lane + 128] : make_int4(0, 0, 0, 0);
    float s = 0.f;
    if (m0.x) s += expf(v0.x - mx);
    if (m0.y) s += expf(v0.y - mx);
    if (m0.z) s += expf(v0.z - mx);
    if (m0.w) s += expf(v0.w - mx);
    if (m1.x) s += expf(v1.x - mx);
    if (m1.y) s += expf(v1.y - mx);
    if (m1.z) s += expf(v1.z - mx);
    if (m1.w) s += expf(v1.w - mx);
    if (m2.x) s += expf(v2.x - mx);
    if (m2.y) s += expf(v2.y - mx);
    if (m2.z) s += expf(v2.z - mx);
    if (m2.w) s += expf(v2.w - mx);
    #pragma unroll
    for (int off = 32; off >= 1; off >>= 1)
        s += __shfl_xor(s, off);

    // ---------------- cls loss row (width-32 groups, both halves dup) ----
    float x = tag_logits[(size_t)row * CC + (lane & 31)];
    float cm = x;
    #pragma unroll
    for (int off = 16; off >= 1; off >>= 1)
        cm = fmaxf(cm, __shfl_xor(cm, off, 32));
    float cs = expf(x - cm);
    #pragma unroll
    for (int off = 16; off >= 1; off >>= 1)
        cs += __shfl_xor(cs, off, 32);
    const int tgt = tag_targets[row];
    const float xt = __shfl(x, tgt, 32);

    if (lane == 0) {
        // pointer: gathered targets, set semantics, !=0 counting
        const float denom = s + 1e-10f;
        const int* bx = box + (size_t)row * MM;
        int t0 = -1, t1 = -1, t2 = -1;
        float lsum = 0.f;
        int lcnt = 0;
        #pragma unroll
        for (int mi = 0; mi < MM; ++mi) {
            int t = bx[mi];
            if (t < 0) continue;
            if (t > LL - 1) t = LL - 1;
            if (t == t0 || t == t1 || t == t2) continue;
            if (t0 < 0) t0 = t; else if (t1 < 0) t1 = t; else t2 = t;
            if (!mrow[t]) continue;
            const float xj = pl[(size_t)row * LL + t];
            const float p = expf(xj - mx) / denom + 1e-10f;
            const float v = -logf(p);
            lsum += v;
            if (v != 0.0f) lcnt++;
        }
        // bce element for row
        const int off2  = b * (2 * LL) + LL + j;
        const int seq2  = am[off2];
        const int data2 = dtm[off2];
        const float xe  = epl[row];
        const float te  = (seq2 && !data2) ? 1.f : 0.f;
        const float bce = fmaxf(xe, 0.f) - xe * te + log1pf(expf(-fabsf(xe)));

        red[wave][0] = (cm + logf(cs)) - xt;   // cls
        red[wave][1] = lsum;                   // ptr sum
        red[wave][2] = (float)lcnt;            // ptr cnt
        red[wave][3] = seq2 ? bce : 0.f;       // bce sum
        red[wave][4] = seq2 ? 1.f : 0.f;       // vm sum
    }
    __syncthreads();
    if (threadIdx.x == 0) {
        Partial p;
        p.a.x = red[0][0] + red[1][0] + red[2][0] + red[3][0];
        p.a.y = red[0][1] + red[1][1] + red[2][1] + red[3][1];
        p.a.z = red[0][2] + red[1][2] + red[2][2] + red[3][2];
        p.a.w = red[0][3] + red[1][3] + red[2][3] + red[3][3];
        p.b = make_float4(red[0][4] + red[1][4] + red[2][4] + red[3][4], 0.f, 0.f, 0.f);
        partials[blockIdx.x] = p;
    }
}

// Reduce 5504 partials -> 4 outputs. One block, 1024 threads (16 waves).
__global__ __launch_bounds__(1024) void reduce_kernel(const Partial* __restrict__ partials,
                                                      float* __restrict__ out)
{
    __shared__ float sm[16][5];
    float cls = 0.f, ptr = 0.f, cnt = 0.f, bce = 0.f, vm = 0.f;
    for (int i = threadIdx.x; i < NBLK; i += 1024) {
        const Partial p = partials[i];
        cls += p.a.x; ptr += p.a.y; cnt += p.a.z; bce += p.a.w; vm += p.b.x;
    }
    #pragma unroll
    for (int off = 32; off >= 1; off >>= 1) {
        cls += __shfl_xor(cls, off);
        ptr += __shfl_xor(ptr, off);
        cnt += __shfl_xor(cnt, off);
        bce += __shfl_xor(bce, off);
        vm  += __shfl_xor(vm,  off);
    }
    const int wv = threadIdx.x >> 6;
    if ((threadIdx.x & 63) == 0) {
        sm[wv][0] = cls; sm[wv][1] = ptr; sm[wv][2] = cnt;
        sm[wv][3] = bce; sm[wv][4] = vm;
    }
    __syncthreads();
    if (threadIdx.x == 0) {
        float tc = 0.f, tp = 0.f, tn = 0.f, tb = 0.f, tv = 0.f;
        #pragma unroll
        for (int i = 0; i < 16; ++i) {
            tc += sm[i][0]; tp += sm[i][1]; tn += sm[i][2];
            tb += sm[i][3]; tv += sm[i][4];
        }
        const float cls_loss = tc / (float)ROWS;
        const float ptr_loss = (tn == 0.f) ? 0.f : tp / fmaxf(tn, 1.f);
        const float emp_loss = tb / fmaxf(tv, 1.f);
        out[0] = cls_loss + ptr_loss + emp_loss;
        out[1] = cls_loss;
        out[2] = ptr_loss;
        out[3] = emp_loss;
    }
}

extern "C" void kernel_launch(void* const* d_in, const int* in_sizes, int n_in,
                              void* d_out, int out_size, void* d_ws, size_t ws_size,
                              hipStream_t stream) {
    const float* tag_logits           = (const float*)d_in[0];
    const float* pointer_logits       = (const float*)d_in[1];
    const float* empty_pointer_logits = (const float*)d_in[2];
    const int*   tag_targets          = (const int*)d_in[3];
    const int*   box_indices          = (const int*)d_in[4];
    const int*   data_tag_mask        = (const int*)d_in[5];
    const int*   attention_mask       = (const int*)d_in[6];
    float* out = (float*)d_out;
    Partial* partials = (Partial*)d_ws;

    fused_kernel<<<NBLK, 256, 0, stream>>>(tag_logits, pointer_logits,
                                           empty_pointer_logits, tag_targets,
                                           box_indices, data_tag_mask,
                                           attention_mask, partials);
    reduce_kernel<<<1, 1024, 0, stream>>>(partials, out);
}

// Round 4
// 108.478 us; speedup vs baseline: 4.0047x; 1.0959x over previous
//
#include <hip/hip_runtime.h>
#include <hip/hip_bf16.h>
#include <math.h>

// Problem constants: B=32, L=688, M=4, C=32
#define BB 32
#define LL 688
#define MM 4
#define CC 32
#define ROWS (BB * LL)        // 22016
#define RPW 4                 // rows per wave
#define WPB 4                 // waves per block (256 threads)
#define RPB (RPW * WPB)       // 16 rows per block
#define NBLK (ROWS / RPB)     // 1376 blocks

struct Partial { float4 a; float4 b; };  // a={cls,ptr,cnt,bce} b={vm,-,-,-}

__device__ __forceinline__ float max12(float4 x, float4 y, float4 z) {
    return fmaxf(fmaxf(fmaxf(fmaxf(x.x, x.y), fmaxf(x.z, x.w)),
                       fmaxf(fmaxf(y.x, y.y), fmaxf(y.z, y.w))),
                 fmaxf(fmaxf(z.x, z.y), fmaxf(z.z, z.w)));
}

__device__ __forceinline__ float msum12(float4 x, float4 y, float4 z,
                                        float4 f0, float4 f1, float4 f2, float m) {
    float s = 0.f;
    s = fmaf(f0.x, __expf(x.x - m), s);
    s = fmaf(f0.y, __expf(x.y - m), s);
    s = fmaf(f0.z, __expf(x.z - m), s);
    s = fmaf(f0.w, __expf(x.w - m), s);
    s = fmaf(f1.x, __expf(y.x - m), s);
    s = fmaf(f1.y, __expf(y.y - m), s);
    s = fmaf(f1.z, __expf(y.z - m), s);
    s = fmaf(f1.w, __expf(y.w - m), s);
    s = fmaf(f2.x, __expf(z.x - m), s);
    s = fmaf(f2.y, __expf(z.y - m), s);
    s = fmaf(f2.z, __expf(z.z - m), s);
    s = fmaf(f2.w, __expf(z.w - m), s);
    return s;
}

// One wave64 per 4 consecutive rows (688 % 4 == 0 -> constant batch per wave).
// Computes ptr-row softmax stats (4-way ILP reductions), gathered targets
// (16 lanes in parallel), cls loss (2 half-wave passes), bce (4 lanes).
// Block writes ONE 32B partial. No atomics, no memset.
__global__ __launch_bounds__(256) void fused_kernel(
    const float* __restrict__ tag_logits,
    const float* __restrict__ pl,
    const float* __restrict__ epl,
    const int* __restrict__ tag_targets,
    const int* __restrict__ box,
    const int* __restrict__ dtm,
    const int* __restrict__ am,
    Partial* __restrict__ partials)
{
    __shared__ float red[WPB][5];
    const int wave = threadIdx.x >> 6;
    const int lane = threadIdx.x & 63;
    const int row0 = blockIdx.x * RPB + wave * RPW;
    const int bat  = row0 / LL;
    const int jcol0 = row0 - bat * LL;

    const int* mrow = dtm + bat * (2 * LL) + LL;   // seq_mask[bat, :]
    const int4* maskp = (const int4*)mrow;
    const bool has2 = (lane < 44);                 // 172 - 128

    // masks once per wave (shared by all 4 rows)
    const int4 mi0 = maskp[lane];
    const int4 mi1 = maskp[lane + 64];
    const int4 mi2 = has2 ? maskp[lane + 128] : make_int4(0, 0, 0, 0);
    const float4 f0 = make_float4(mi0.x ? 1.f : 0.f, mi0.y ? 1.f : 0.f,
                                  mi0.z ? 1.f : 0.f, mi0.w ? 1.f : 0.f);
    const float4 f1 = make_float4(mi1.x ? 1.f : 0.f, mi1.y ? 1.f : 0.f,
                                  mi1.z ? 1.f : 0.f, mi1.w ? 1.f : 0.f);
    const float4 f2 = make_float4(mi2.x ? 1.f : 0.f, mi2.y ? 1.f : 0.f,
                                  mi2.z ? 1.f : 0.f, mi2.w ? 1.f : 0.f);

    const float4 NEGV = make_float4(-INFINITY, -INFINITY, -INFINITY, -INFINITY);
    const float4* rp0 = (const float4*)(pl + (size_t)(row0 + 0) * LL);
    const float4* rp1 = (const float4*)(pl + (size_t)(row0 + 1) * LL);
    const float4* rp2 = (const float4*)(pl + (size_t)(row0 + 2) * LL);
    const float4* rp3 = (const float4*)(pl + (size_t)(row0 + 3) * LL);

    // issue all 12 row loads up front
    const float4 a0 = rp0[lane], a1 = rp0[lane + 64], a2 = has2 ? rp0[lane + 128] : NEGV;
    const float4 c0 = rp1[lane], c1 = rp1[lane + 64], c2 = has2 ? rp1[lane + 128] : NEGV;
    const float4 d0 = rp2[lane], d1 = rp2[lane + 64], d2 = has2 ? rp2[lane + 128] : NEGV;
    const float4 e0 = rp3[lane], e1 = rp3[lane + 64], e2 = has2 ? rp3[lane + 128] : NEGV;

    // per-lane maxes, then 4 interleaved wave reductions (independent chains)
    float pm0 = max12(a0, a1, a2);
    float pm1 = max12(c0, c1, c2);
    float pm2 = max12(d0, d1, d2);
    float pm3 = max12(e0, e1, e2);
    #pragma unroll
    for (int off = 32; off >= 1; off >>= 1) {
        pm0 = fmaxf(pm0, __shfl_xor(pm0, off));
        pm1 = fmaxf(pm1, __shfl_xor(pm1, off));
        pm2 = fmaxf(pm2, __shfl_xor(pm2, off));
        pm3 = fmaxf(pm3, __shfl_xor(pm3, off));
    }

    float ps0 = msum12(a0, a1, a2, f0, f1, f2, pm0);
    float ps1 = msum12(c0, c1, c2, f0, f1, f2, pm1);
    float ps2 = msum12(d0, d1, d2, f0, f1, f2, pm2);
    float ps3 = msum12(e0, e1, e2, f0, f1, f2, pm3);
    #pragma unroll
    for (int off = 32; off >= 1; off >>= 1) {
        ps0 += __shfl_xor(ps0, off);
        ps1 += __shfl_xor(ps1, off);
        ps2 += __shfl_xor(ps2, off);
        ps3 += __shfl_xor(ps3, off);
    }

    // ---- pointer tail: 16 logical lanes = 4 rows x 4 box slots ----
    const int rl  = lane & 15;           // lanes 16+ duplicate (keeps shfl safe)
    const int r   = rl >> 2;
    const int mi  = rl & 3;
    const int rowr = row0 + r;
    const float mxr = (r == 0) ? pm0 : (r == 1) ? pm1 : (r == 2) ? pm2 : pm3;
    const float dnr = ((r == 0) ? ps0 : (r == 1) ? ps1 : (r == 2) ? ps2 : ps3) + 1e-10f;

    const int t = box[(size_t)rowr * MM + mi];
    const int ta  = __shfl(t, (lane & ~3));
    const int tb  = __shfl(t, (lane & ~3) + 1);
    const int tc2 = __shfl(t, (lane & ~3) + 2);
    const bool dup = (mi > 0 && t == ta) || (mi > 1 && t == tb) || (mi > 2 && t == tc2);
    const bool valid = (t >= 0);
    const int tcl = t < 0 ? 0 : (t > LL - 1 ? LL - 1 : t);

    float contrib = 0.f, ccnt = 0.f;
    if (valid && !dup && mrow[tcl]) {
        const float xj = pl[(size_t)rowr * LL + tcl];
        const float p = __expf(xj - mxr) / dnr + 1e-10f;
        const float v = -__logf(p);
        contrib = v;
        ccnt = (v != 0.0f) ? 1.f : 0.f;
    }
    contrib += __shfl_xor(contrib, 1); contrib += __shfl_xor(contrib, 2);
    ccnt    += __shfl_xor(ccnt, 1);    ccnt    += __shfl_xor(ccnt, 2);
    const float ptr_sum = __shfl(contrib, 0) + __shfl(contrib, 4) +
                          __shfl(contrib, 8) + __shfl(contrib, 12);
    const float ptr_cnt = __shfl(ccnt, 0) + __shfl(ccnt, 4) +
                          __shfl(ccnt, 8) + __shfl(ccnt, 12);

    // ---- cls: 2 passes, half-wave per row ----
    float cls_tot = 0.f;
    #pragma unroll
    for (int pass = 0; pass < 2; ++pass) {
        const int rowc = row0 + pass * 2 + (lane >> 5);
        const float x = tag_logits[(size_t)rowc * CC + (lane & 31)];
        float cm = x;
        #pragma unroll
        for (int off = 16; off >= 1; off >>= 1)
            cm = fmaxf(cm, __shfl_xor(cm, off, 32));
        float cs = __expf(x - cm);
        #pragma unroll
        for (int off = 16; off >= 1; off >>= 1)
            cs += __shfl_xor(cs, off, 32);
        const int tg = tag_targets[rowc];
        const float xt = __shfl(x, tg + (lane & 32));
        const float c = (cm + __logf(cs)) - xt;
        cls_tot += __shfl(c, 0) + __shfl(c, 32);
    }

    // ---- bce: nibble lanes handle rows 0-3 ----
    const int rb = lane & 3;
    const int rowb = row0 + rb;
    const int offb = bat * (2 * LL) + LL + (jcol0 + rb);
    const int seq2  = am[offb];
    const int data2 = dtm[offb];
    const float xe = epl[rowb];
    const float te = (seq2 && !data2) ? 1.f : 0.f;
    const float bce = fmaxf(xe, 0.f) - xe * te + log1pf(__expf(-fabsf(xe)));
    float bsum = seq2 ? bce : 0.f;
    float vsum = seq2 ? 1.f : 0.f;
    bsum += __shfl_xor(bsum, 1); bsum += __shfl_xor(bsum, 2);
    vsum += __shfl_xor(vsum, 1); vsum += __shfl_xor(vsum, 2);

    if (lane == 0) {
        red[wave][0] = cls_tot;
        red[wave][1] = ptr_sum;
        red[wave][2] = ptr_cnt;
        red[wave][3] = bsum;
        red[wave][4] = vsum;
    }
    __syncthreads();
    if (threadIdx.x == 0) {
        Partial p;
        p.a.x = red[0][0] + red[1][0] + red[2][0] + red[3][0];
        p.a.y = red[0][1] + red[1][1] + red[2][1] + red[3][1];
        p.a.z = red[0][2] + red[1][2] + red[2][2] + red[3][2];
        p.a.w = red[0][3] + red[1][3] + red[2][3] + red[3][3];
        p.b = make_float4(red[0][4] + red[1][4] + red[2][4] + red[3][4], 0.f, 0.f, 0.f);
        partials[blockIdx.x] = p;
    }
}

// Reduce 1376 partials (44 KB) -> 4 outputs. One block, 256 threads.
__global__ __launch_bounds__(256) void reduce_kernel(const Partial* __restrict__ partials,
                                                     float* __restrict__ out)
{
    __shared__ float sm[4][5];
    float c = 0.f, p = 0.f, n = 0.f, e = 0.f, v = 0.f;
    for (int i = threadIdx.x; i < NBLK; i += 256) {
        const Partial q = partials[i];
        c += q.a.x; p += q.a.y; n += q.a.z; e += q.a.w; v += q.b.x;
    }
    #pragma unroll
    for (int off = 32; off >= 1; off >>= 1) {
        c += __shfl_xor(c, off);
        p += __shfl_xor(p, off);
        n += __shfl_xor(n, off);
        e += __shfl_xor(e, off);
        v += __shfl_xor(v, off);
    }
    const int wv = threadIdx.x >> 6;
    if ((threadIdx.x & 63) == 0) {
        sm[wv][0] = c; sm[wv][1] = p; sm[wv][2] = n; sm[wv][3] = e; sm[wv][4] = v;
    }
    __syncthreads();
    if (threadIdx.x == 0) {
        float tc = 0.f, tp = 0.f, tn = 0.f, tb = 0.f, tv = 0.f;
        #pragma unroll
        for (int i = 0; i < 4; ++i) {
            tc += sm[i][0]; tp += sm[i][1]; tn += sm[i][2];
            tb += sm[i][3]; tv += sm[i][4];
        }
        const float cls_loss = tc / (float)ROWS;
        const float ptr_loss = (tn == 0.f) ? 0.f : tp / fmaxf(tn, 1.f);
        const float emp_loss = tb / fmaxf(tv, 1.f);
        out[0] = cls_loss + ptr_loss + emp_loss;
        out[1] = cls_loss;
        out[2] = ptr_loss;
        out[3] = emp_loss;
    }
}

extern "C" void kernel_launch(void* const* d_in, const int* in_sizes, int n_in,
                              void* d_out, int out_size, void* d_ws, size_t ws_size,
                              hipStream_t stream) {
    const float* tag_logits           = (const float*)d_in[0];
    const float* pointer_logits       = (const float*)d_in[1];
    const float* empty_pointer_logits = (const float*)d_in[2];
    const int*   tag_targets          = (const int*)d_in[3];
    const int*   box_indices          = (const int*)d_in[4];
    const int*   data_tag_mask        = (const int*)d_in[5];
    const int*   attention_mask       = (const int*)d_in[6];
    float* out = (float*)d_out;
    Partial* partials = (Partial*)d_ws;

    fused_kernel<<<NBLK, 256, 0, stream>>>(tag_logits, pointer_logits,
                                           empty_pointer_logits, tag_targets,
                                           box_indices, data_tag_mask,
                                           attention_mask, partials);
    reduce_kernel<<<1, 256, 0, stream>>>(partials, out);
}